// Round 11
// baseline (204.408 us; speedup 1.0000x reference)
//
#include <hip/hip_runtime.h>

typedef int i32x4 __attribute__((ext_vector_type(4)));

#define CAP 12
#define SE_SCALE 130048.0f   // 1024*127: |e|<1/1024 -> |e_i8| <= 127

// ws layout (bytes)
#define WS_LOSS 0
#define WS_DONE 8
#define WS_EBI8 64        // 1024 codes x 64 i8 (B-permuted) = 65536 -> 65600
#define WS_SZ   65600     // 65536 floats (127/max|z|)        -> 327744
#define WS_MI   327744    // 65536 ints (integer margin)      -> 589888
#define WS_CNT  589888    // 65536 ints                       -> 852032
#define WS_CAND 852032    // 65536*CAP ushorts = 1572864      -> 2424896

// numpy pairwise sum-of-squares (n=64), exact op order (R2-proven).
__device__ __forceinline__ float np_pairwise_sumsq64_p(const float* __restrict__ a) {
    float r[8];
    #pragma unroll
    for (int i = 0; i < 64; i += 8)
        #pragma unroll
        for (int jj = 0; jj < 2; ++jj) {
            float4 v = *(const float4*)(a + i + jj * 4);
            float vv[4] = {v.x, v.y, v.z, v.w};
            #pragma unroll
            for (int m = 0; m < 4; ++m) {
                int j = jj * 4 + m;
                float sq = __fmul_rn(vv[m], vv[m]);
                r[j] = (i == 0) ? sq : __fadd_rn(r[j], sq);
            }
        }
    return __fadd_rn(
        __fadd_rn(__fadd_rn(r[0], r[1]), __fadd_rn(r[2], r[3])),
        __fadd_rn(__fadd_rn(r[4], r[5]), __fadd_rn(r[6], r[7])));
}

// exact numpy fp32 score (R2-proven): round(znorm+enorm) - 2*dot
__device__ __forceinline__ float exact_score(const float* __restrict__ z, float znorm,
                                             const float* __restrict__ emb, int k) {
    const float* ep = emb + k * 64;
    float en = np_pairwise_sumsq64_p(ep);
    float acc = 0.0f;
    #pragma unroll
    for (int j = 0; j < 16; ++j) {
        float4 v = *(const float4*)(ep + j * 4);
        acc = fmaf(z[4*j+0], v.x, acc);
        acc = fmaf(z[4*j+1], v.y, acc);
        acc = fmaf(z[4*j+2], v.z, acc);
        acc = fmaf(z[4*j+3], v.w, acc);
    }
    return __fsub_rn(__fadd_rn(znorm, en), __fmul_rn(2.0f, acc));
}

// K1a: per-position scale s_z = 127/max|z|, integer margin Mi, cnt=0.
__global__ __launch_bounds__(256) void prep_z_kernel(
    const float* __restrict__ ze, float* __restrict__ sz, int* __restrict__ mi,
    int* __restrict__ cnt, float* __restrict__ loss, int* __restrict__ done)
{
    int n = blockIdx.x * 256 + threadIdx.x;   // grid 256 -> 65536
    if (n == 0) { *loss = 0.0f; *done = 0; }
    cnt[n] = 0;
    const float* zp = ze + ((n >> 12) * 262144 + (n & 4095));
    float S = 0.0f, mx = 1e-20f;
    #pragma unroll
    for (int l = 0; l < 64; ++l) {
        float v = fabsf(zp[l * 4096]);
        S += v; mx = fmaxf(mx, v);
    }
    sz[n] = 127.0f / mx;
    // marg_dot = 2*(dz*sum|e| + de*sum|z|) + en-spread + np-rounding + safety
    float marg = 2.0f * (2.5e-4f * mx + 3.9e-6f * S) + 1.2e-4f;
    mi[n] = (int)ceilf(marg * (127.0f / mx) * SE_SCALE) + 1;
}

// K1b: i8 codebook in MFMA-B-permuted layout:
// ebi8[tile(64)][q(4)][r(16)][16 i8], code = tile*16+r, k = q*16+j.
__global__ __launch_bounds__(256) void prep_e_kernel(
    const float* __restrict__ emb, unsigned char* __restrict__ ebi8)
{
    int k = blockIdx.x * 256 + threadIdx.x;   // grid 4 -> 1024
    if (k < 1024) {
        int tile = k >> 4, r = k & 15;
        #pragma unroll
        for (int q = 0; q < 4; ++q) {
            int w[4];
            #pragma unroll
            for (int c = 0; c < 4; ++c) {
                int acc = 0;
                #pragma unroll
                for (int b = 0; b < 4; ++b) {
                    int iv = (int)rintf(emb[k * 64 + q * 16 + c * 4 + b] * SE_SCALE);
                    acc |= (iv & 0xff) << (8 * b);
                }
                w[c] = acc;
            }
            *(int4*)(ebi8 + tile * 1024 + q * 256 + r * 16) = make_int4(w[0], w[1], w[2], w[3]);
        }
    }
}

// K2: i8 MFMA filter. Grid 512 (= 2 blocks/CU, ALL co-resident, 1 generation).
// Block = 128 positions x all 1024 codes; full i8 codebook in 64 KB LDS.
// Per tile: 1 ds_read_b128 + 2 independent K=64 MFMAs (no chain) + 8 v_max.
__global__ __launch_bounds__(256) void vq_filter_kernel(
    const float* __restrict__ ze, const unsigned char* __restrict__ ebi8,
    const float* __restrict__ sz, const int* __restrict__ mi,
    int* __restrict__ cnt, unsigned short* __restrict__ cand)
{
    __shared__ __align__(16) unsigned char ebl[65536];   // exactly 64 KB

    const int t = threadIdx.x;
    const int n0 = blockIdx.x * 128;
    const int gbase = (n0 >> 12) * 262144 + (n0 & 4095);

    const int wv = t >> 6, lane = t & 63;
    const int r = lane & 15, q = lane >> 4;
    const int wp = wv * 32;

    // ---- A-fragments: quantize z on the fly. A[m=lane&15][k=q*16+j] ----
    i32x4 a0, a1;
    #pragma unroll
    for (int rg = 0; rg < 2; ++rg) {
        const int row = wp + rg * 16 + r;
        const float s = sz[n0 + row];
        const float* zb = ze + gbase + row;
        int w[4];
        #pragma unroll
        for (int c = 0; c < 4; ++c) {
            int acc = 0;
            #pragma unroll
            for (int b = 0; b < 4; ++b) {
                int iv = (int)rintf(zb[(q * 16 + c * 4 + b) * 4096] * s);
                acc |= (iv & 0xff) << (8 * b);
            }
            w[c] = acc;
        }
        i32x4 av = {w[0], w[1], w[2], w[3]};
        if (rg == 0) a0 = av; else a1 = av;
    }

    // ---- stage full i8 codebook (65536 B) ----
    {
        const int4* src = (const int4*)ebi8;
        int4* dst = (int4*)ebl;
        #pragma unroll 8
        for (int i = 0; i < 16; ++i) dst[t + i * 256] = src[t + i * 256];
    }
    __syncthreads();

    const unsigned char* bptr = ebl + q * 256 + r * 16;
    const i32x4 zero = {0, 0, 0, 0};

    // ---- pass 1: per-row integer max of c = zq . eq over all 1024 codes ----
    int rm[8];
    #pragma unroll
    for (int i = 0; i < 8; ++i) rm[i] = (int)0x80000000;
    {
        i32x4 pb[4];
        #pragma unroll
        for (int i = 0; i < 4; ++i) pb[i] = *(const i32x4*)(bptr + i * 1024);
        #pragma unroll 4
        for (int tile = 0; tile < 64; ++tile) {
            i32x4 b = pb[tile & 3];
            int nt = tile + 4; if (nt > 63) nt = 63;
            pb[tile & 3] = *(const i32x4*)(bptr + nt * 1024);
            i32x4 c0 = __builtin_amdgcn_mfma_i32_16x16x64_i8(a0, b, zero, 0, 0, 0);
            i32x4 c1 = __builtin_amdgcn_mfma_i32_16x16x64_i8(a1, b, zero, 0, 0, 0);
            #pragma unroll
            for (int i = 0; i < 4; ++i) {
                rm[i]     = max(rm[i],     c0[i]);
                rm[4 + i] = max(rm[4 + i], c1[i]);
            }
        }
    }
    int thr[8];
    #pragma unroll
    for (int j = 0; j < 8; ++j) {
        int v = rm[j];
        v = max(v, __shfl_xor(v, 1, 16));
        v = max(v, __shfl_xor(v, 2, 16));
        v = max(v, __shfl_xor(v, 4, 16));
        v = max(v, __shfl_xor(v, 8, 16));
        int row = wp + (j >> 2) * 16 + q * 4 + (j & 3);
        thr[j] = v - mi[n0 + row];
    }

    // ---- pass 2: collect candidates (c >= rowmax - Mi) ----
    {
        i32x4 pb[4];
        #pragma unroll
        for (int i = 0; i < 4; ++i) pb[i] = *(const i32x4*)(bptr + i * 1024);
        #pragma unroll 4
        for (int tile = 0; tile < 64; ++tile) {
            i32x4 b = pb[tile & 3];
            int nt = tile + 4; if (nt > 63) nt = 63;
            pb[tile & 3] = *(const i32x4*)(bptr + nt * 1024);
            i32x4 c0 = __builtin_amdgcn_mfma_i32_16x16x64_i8(a0, b, zero, 0, 0, 0);
            i32x4 c1 = __builtin_amdgcn_mfma_i32_16x16x64_i8(a1, b, zero, 0, 0, 0);
            int code = tile * 16 + r;
            #pragma unroll
            for (int i = 0; i < 4; ++i) {
                if (c0[i] >= thr[i]) {
                    int gp = n0 + wp + q * 4 + i;
                    int ci = atomicAdd(&cnt[gp], 1);
                    if (ci < CAP) cand[gp * CAP + ci] = (unsigned short)code;
                }
                if (c1[i] >= thr[4 + i]) {
                    int gp = n0 + wp + 16 + q * 4 + i;
                    int ci = atomicAdd(&cnt[gp], 1);
                    if (ci < CAP) cand[gp * CAP + ci] = (unsigned short)code;
                }
            }
        }
    }
}

// K3: exact fp32 numpy rescore + select + z_q/loss epilogue + finalize.
// Overflowed positions handled block-cooperatively (R10-proven).
__global__ __launch_bounds__(256) void rescore_kernel(
    const float* __restrict__ ze, const float* __restrict__ emb,
    const int* __restrict__ cnt, const unsigned short* __restrict__ cand,
    float* __restrict__ out_zq, float* __restrict__ out_idxf,
    float* __restrict__ loss, int* __restrict__ done,
    float* __restrict__ out_loss)
{
    __shared__ int   ovf_list[256];
    __shared__ int   ovf_cnt;
    __shared__ float zsh[64];
    __shared__ float znorm_sh;
    __shared__ float red_s[256];
    __shared__ int   red_k[256];
    __shared__ int   res_k[256];

    const int t = threadIdx.x;
    const int n0 = blockIdx.x * 256;
    const int gbase = (n0 >> 12) * 262144 + (n0 & 4095);
    const int n = n0 + t;
    if (t == 0) ovf_cnt = 0;
    __syncthreads();

    float z[64];
    const float* zp = ze + gbase + t;
    #pragma unroll
    for (int l = 0; l < 64; ++l) z[l] = zp[l * 4096];
    const float znorm = np_pairwise_sumsq64_p(z);

    int c0 = cnt[n];
    float best = 1e30f; int bk = 1 << 20;
    if (c0 <= CAP) {
        for (int i = 0; i < c0; ++i) {
            int k = cand[n * CAP + i];
            float sc = exact_score(z, znorm, emb, k);
            if (sc < best || (sc == best && k < bk)) { best = sc; bk = k; }
        }
    } else {
        int pos = atomicAdd(&ovf_cnt, 1);
        ovf_list[pos] = t;
    }
    res_k[t] = bk;
    __syncthreads();

    // block-cooperative exact full scan for overflowed positions
    const int no = ovf_cnt;
    for (int i = 0; i < no; ++i) {
        const int p = ovf_list[i];
        if (t == p) {
            #pragma unroll
            for (int l = 0; l < 64; ++l) zsh[l] = z[l];
            znorm_sh = znorm;
        }
        __syncthreads();
        float b2 = 1e30f; int k2 = 1 << 20;
        #pragma unroll
        for (int j = 0; j < 4; ++j) {
            int k = t + j * 256;   // ascending -> lowest-k on tie
            float sc = exact_score(zsh, znorm_sh, emb, k);
            if (sc < b2) { b2 = sc; k2 = k; }
        }
        red_s[t] = b2; red_k[t] = k2;
        __syncthreads();
        for (int st = 128; st > 0; st >>= 1) {
            if (t < st) {
                float os = red_s[t + st]; int ok = red_k[t + st];
                if (os < red_s[t] || (os == red_s[t] && ok < red_k[t])) {
                    red_s[t] = os; red_k[t] = ok;
                }
            }
            __syncthreads();
        }
        if (t == 0) res_k[p] = red_k[0];
        __syncthreads();
    }

    bk = res_k[t];
    out_idxf[n] = (float)bk;

    // epilogue: z_q gather + loss partial
    {
        const float* er = emb + bk * 64;
        float ls = 0.0f;
        #pragma unroll
        for (int j = 0; j < 16; ++j) {
            float4 v = *(const float4*)(er + j * 4);
            float vv[4] = {v.x, v.y, v.z, v.w};
            #pragma unroll
            for (int m = 0; m < 4; ++m) {
                int l = 4 * j + m;
                out_zq[gbase + t + l * 4096] = vv[m];
                float d = vv[m] - z[l];
                ls = fmaf(d, d, ls);
            }
        }
        #pragma unroll
        for (int off = 32; off > 0; off >>= 1) ls += __shfl_down(ls, off, 64);
        if ((t & 63) == 0) atomicAdd(loss, ls);
    }

    __syncthreads();
    if (t == 0) {
        __threadfence();
        int old = atomicAdd(done, 1);
        if (old == (int)gridDim.x - 1) {
            __threadfence();
            float total = atomicAdd(loss, 0.0f);   // coherent read
            *out_loss = 1.25f * total / 4194304.0f;
        }
    }
}

extern "C" void kernel_launch(void* const* d_in, const int* in_sizes, int n_in,
                              void* d_out, int out_size, void* d_ws, size_t ws_size,
                              hipStream_t stream)
{
    const float* ze  = (const float*)d_in[0];   // (16,64,64,64) fp32
    const float* emb = (const float*)d_in[1];   // (1024,64) fp32
    float* out = (float*)d_out;
    float* out_zq   = out;                 // 4194304
    float* out_loss = out + 4194304;       // 1
    float* out_idxf = out + 4194305;       // 65536

    char* w = (char*)d_ws;
    float*          ws_loss = (float*)(w + WS_LOSS);
    int*            ws_done = (int*)(w + WS_DONE);
    unsigned char*  ebi8    = (unsigned char*)(w + WS_EBI8);
    float*          ws_sz   = (float*)(w + WS_SZ);
    int*            ws_mi   = (int*)(w + WS_MI);
    int*            ws_cnt  = (int*)(w + WS_CNT);
    unsigned short* ws_cand = (unsigned short*)(w + WS_CAND);

    prep_z_kernel<<<256, 256, 0, stream>>>(ze, ws_sz, ws_mi, ws_cnt, ws_loss, ws_done);
    prep_e_kernel<<<4, 256, 0, stream>>>(emb, ebi8);
    vq_filter_kernel<<<512, 256, 0, stream>>>(ze, ebi8, ws_sz, ws_mi, ws_cnt, ws_cand);
    rescore_kernel<<<256, 256, 0, stream>>>(ze, emb, ws_cnt, ws_cand,
                                            out_zq, out_idxf, ws_loss, ws_done, out_loss);
}